// Round 3
// baseline (1408.746 us; speedup 1.0000x reference)
//
#include <hip/hip_runtime.h>
#include <hip/hip_bf16.h>

typedef __attribute__((ext_vector_type(8))) __bf16 bf16x8;
typedef __attribute__((ext_vector_type(4))) float f32x4;

#define MFMA(a,b,c) __builtin_amdgcn_mfma_f32_16x16x32_bf16((a),(b),(c),0,0,0)

__device__ __forceinline__ bf16x8 cvt8(float4 a, float4 b){
  bf16x8 r;
  r[0]=(__bf16)a.x; r[1]=(__bf16)a.y; r[2]=(__bf16)a.z; r[3]=(__bf16)a.w;
  r[4]=(__bf16)b.x; r[5]=(__bf16)b.y; r[6]=(__bf16)b.z; r[7]=(__bf16)b.w;
  return r;
}

// Pack 5 weight matrices [64][64] f32 into bf16 MFMA B-fragments.
// Wp[(m*8 + kt*4 + nt)*64 + lane]: lane holds B[k=kt*32+(l>>4)*8+j][n=nt*16+(l&15)]
__global__ void wcvt(const float* __restrict__ W0, const float* __restrict__ W1,
                     const float* __restrict__ W2, const float* __restrict__ W3,
                     const float* __restrict__ W4, bf16x8* __restrict__ Wp){
  int tid = blockIdx.x*256 + threadIdx.x;
  if (tid >= 5*8*64) return;
  int lane = tid & 63, frag = (tid>>6)&7, m = tid>>9;
  const float* Ws[5] = {W0,W1,W2,W3,W4};
  const float* W = Ws[m];
  int kt = frag>>2, nt = frag&3, g = lane>>4, c = lane&15;
  bf16x8 v;
  #pragma unroll
  for (int j=0;j<8;j++){
    int k = kt*32 + g*8 + j, n = nt*16 + c;
    v[j] = (__bf16)W[k*64+n];
  }
  Wp[tid] = v;
}

// 3 node transforms: e_src, e_dst, A_src
__global__ __launch_bounds__(256) void node_xform(
    const float* __restrict__ nf, const bf16x8* __restrict__ Wp,
    const float* __restrict__ b_sg, const float* __restrict__ b_dg,
    const float* __restrict__ b_su,
    float* __restrict__ e_src, float* __restrict__ e_dst,
    float* __restrict__ A_src, int ntiles)
{
  int lane = threadIdx.x & 63;
  int gw = blockIdx.x*4 + (threadIdx.x>>6);
  if (gw >= ntiles) return;
  int g = lane>>4, c = lane&15;
  long base = (long)gw*16;
  const float* rp = nf + (base + c)*64 + g*8;
  float4 a0 = *(const float4*)rp,      a1 = *(const float4*)(rp+4);
  float4 a2 = *(const float4*)(rp+32), a3 = *(const float4*)(rp+36);
  bf16x8 A0 = cvt8(a0,a1), A1 = cvt8(a2,a3);
  const float* biases[3] = {b_sg,b_dg,b_su};
  float* outs[3] = {e_src,e_dst,A_src};
  const int mats[3] = {0,1,3};
  #pragma unroll
  for (int i=0;i<3;i++){
    #pragma unroll
    for (int nt=0;nt<4;nt++){
      f32x4 acc = {0.f,0.f,0.f,0.f};
      acc = MFMA(A0, Wp[(mats[i]*8+nt)*64+lane],   acc);
      acc = MFMA(A1, Wp[(mats[i]*8+4+nt)*64+lane], acc);
      int col = c + nt*16;
      float bb = biases[i][col];
      #pragma unroll
      for (int e=0;e<4;e++){
        long row = base + 4*g + e;
        outs[i][row*64 + col] = acc[e] + bb;
      }
    }
  }
}

// ---- CSR build on dst ----
__global__ void hist_k(const int* __restrict__ dst, int* __restrict__ cnt, int E){
  int i = blockIdx.x*256 + threadIdx.x, st = gridDim.x*256;
  for (; i<E; i+=st) atomicAdd(&cnt[dst[i]], 1);
}

__global__ __launch_bounds__(1024) void scan_k(const int* __restrict__ cnt,
                                               int* __restrict__ row, int Nn){
  __shared__ int part[1024];
  int t = threadIdx.x;
  int C = (Nn + 1023) >> 10;
  int lo = t*C;
  int hi = lo + C; if (hi > Nn) hi = Nn;
  int s = 0;
  for (int i=lo; i<hi; i++) s += cnt[i];
  part[t] = s;
  __syncthreads();
  for (int off=1; off<1024; off<<=1){
    int v = part[t];
    int u = (t>=off) ? part[t-off] : 0;
    __syncthreads();
    part[t] = v + u;
    __syncthreads();
  }
  int excl = (t==0) ? 0 : part[t-1];
  for (int i=lo; i<hi; i++){ row[i] = excl; excl += cnt[i]; }
  if (t==1023) row[Nn] = excl;
}

__global__ void fill_k(const int* __restrict__ src, const int* __restrict__ dst,
                       const int* __restrict__ row, int* __restrict__ cnt2,
                       int2* __restrict__ pairs, int E){
  int i = blockIdx.x*256 + threadIdx.x, st = gridDim.x*256;
  for (; i<E; i+=st){
    int d = dst[i];
    int pos = row[d] + atomicAdd(&cnt2[d], 1);
    pairs[pos] = make_int2(i, src[i]);
  }
}

// ---- Gather aggregation v2: one wave per node, gather {ef,nf} rows only,
// recompute e_src/Bh contributions via MFMA against LDS-staged weights.
__global__ __launch_bounds__(256,4) void aggregate(
    const float* __restrict__ ef, const float* __restrict__ nf,
    const int2* __restrict__ pairs, const int* __restrict__ row,
    const float* __restrict__ e_dst,
    const float* __restrict__ b_sg, const float* __restrict__ b_eg,
    const float* __restrict__ b_du,
    const bf16x8* __restrict__ Wp,
    float* __restrict__ A_src,            // in/out: A_src -> x_pre
    float* __restrict__ est, float* __restrict__ nst, int Nn)
{
  __shared__ bf16x8 wl[24*64];   // frags: 0-7 W_eg, 8-15 W_sg, 16-23 W_du
  __shared__ float sst[256];
  {
    int t = threadIdx.x;
    #pragma unroll
    for (int i=0;i<6;i++){
      int idx = i*256 + t;
      int frag = idx>>6, lane = idx&63;
      int mi = frag>>3, f = frag&7;
      int mat = (mi==0) ? 2 : (mi==1 ? 0 : 4);
      wl[idx] = Wp[(mat*8+f)*64+lane];
    }
    sst[t] = 0.f;
  }
  __syncthreads();

  int lane = threadIdx.x & 63;
  int gw = blockIdx.x*4 + (threadIdx.x>>6);
  int nw = gridDim.x*4;
  int g = lane>>4, c = lane&15;
  float bsg[4], beg[4], bdu[4];
  #pragma unroll
  for (int nt=0;nt<4;nt++){
    int col = c + nt*16;
    bsg[nt]=b_sg[col]; beg[nt]=b_eg[col]; bdu[nt]=b_du[col];
  }
  float es1[4]={0,0,0,0}, es2[4]={0,0,0,0};
  float ns1=0.f, ns2=0.f;

  for (int n=gw; n<Nn; n+=nw){
    int r0 = row[n];
    int deg = row[n+1] - r0;
    float ed[4];
    #pragma unroll
    for (int nt=0;nt<4;nt++) ed[nt] = e_dst[(long)n*64 + c + nt*16];
    float ssa[4]={0,0,0,0}, ssha[4]={0,0,0,0};
    for (int base=0; base<deg; base+=16){
      int s = base + c;
      int slot = (s < deg) ? s : 0;
      int2 pr = pairs[r0 + slot];
      const float* rpe = ef + (long)pr.x*64 + g*8;
      const float* rpn = nf + (long)pr.y*64 + g*8;
      float4 e0=*(const float4*)rpe,      e1=*(const float4*)(rpe+4);
      float4 e2=*(const float4*)(rpe+32), e3=*(const float4*)(rpe+36);
      float4 n0=*(const float4*)rpn,      n1=*(const float4*)(rpn+4);
      float4 n2=*(const float4*)(rpn+32), n3=*(const float4*)(rpn+36);
      bf16x8 AE0=cvt8(e0,e1), AE1=cvt8(e2,e3);
      bf16x8 AN0=cvt8(n0,n1), AN1=cvt8(n2,n3);
      int rem = deg - base;
      #pragma unroll
      for (int nt=0;nt<4;nt++){
        f32x4 aM={0.f,0.f,0.f,0.f}, aS={0.f,0.f,0.f,0.f}, aB={0.f,0.f,0.f,0.f};
        aM = MFMA(AE0, wl[(   nt)*64+lane], aM);
        aM = MFMA(AE1, wl[( 4+nt)*64+lane], aM);
        aS = MFMA(AN0, wl[( 8+nt)*64+lane], aS);
        aS = MFMA(AN1, wl[(12+nt)*64+lane], aS);
        aB = MFMA(AN0, wl[(16+nt)*64+lane], aB);
        aB = MFMA(AN1, wl[(20+nt)*64+lane], aB);
        #pragma unroll
        for (int e=0;e<4;e++){
          if (4*g+e < rem){
            float esv = aS[e] + bsg[nt];
            float mv = ((aM[e] + esv) + ed[nt]) + beg[nt];
            float sg = 1.f/(1.f+__expf(-mv));
            ssa[nt]  += sg;
            ssha[nt] += (aB[e] + bdu[nt])*sg;
            es1[nt]  += mv;
            es2[nt]  += mv*mv;
          }
        }
      }
    }
    #pragma unroll
    for (int nt=0;nt<4;nt++){
      ssa[nt]  += __shfl_xor(ssa[nt],16,64);  ssa[nt]  += __shfl_xor(ssa[nt],32,64);
      ssha[nt] += __shfl_xor(ssha[nt],16,64); ssha[nt] += __shfl_xor(ssha[nt],32,64);
    }
    float sv  = (g==0)?ssa[0] :(g==1)?ssa[1] :(g==2)?ssa[2] :ssa[3];
    float shv = (g==0)?ssha[0]:(g==1)?ssha[1]:(g==2)?ssha[2]:ssha[3];
    float h = shv/(sv+1e-6f);
    long xi = (long)n*64 + c + 16*g;
    float xp = A_src[xi] + h;
    A_src[xi] = xp;
    ns1 += xp; ns2 += xp*xp;
  }

  __syncthreads();   // sst zero done long ago; ensure all waves ready
  #pragma unroll
  for (int nt=0;nt<4;nt++){
    atomicAdd(&sst[c+16*nt],    es1[nt]);
    atomicAdd(&sst[64+c+16*nt], es2[nt]);
  }
  atomicAdd(&sst[128 + c + 16*g], ns1);
  atomicAdd(&sst[192 + c + 16*g], ns2);
  __syncthreads();
  if (threadIdx.x < 128) atomicAdd(&est[threadIdx.x], sst[threadIdx.x]);
  else                   atomicAdd(&nst[threadIdx.x-128], sst[threadIdx.x]);
}

// Final x = node_feats + silu(bn(x_pre))
__global__ __launch_bounds__(256) void node_final(
    const float* __restrict__ nf, const float* __restrict__ xpre,
    const float* __restrict__ nst, const float* __restrict__ gam,
    const float* __restrict__ bet, float* __restrict__ xo, int Nn)
{
  long tid = blockIdx.x*blockDim.x + threadIdx.x;
  long stride = (long)gridDim.x*blockDim.x;
  int col = (int)(tid & 63);
  float invN = 1.f/(float)Nn;
  float mu = nst[col]*invN;
  float var = nst[64+col]*invN - mu*mu;
  float rs = rsqrtf(var + 1e-5f);
  float aa = gam[col]*rs;
  float bb = bet[col] - mu*aa;
  long total = (long)Nn*64;
  for (long i=tid; i<total; i+=stride){
    float z = xpre[i]*aa + bb;
    xo[i] = nf[i] + z/(1.f+__expf(-z));
  }
}

// Pass 2 over edges: recompute m, y = ef + silu(bn(m))
__global__ __launch_bounds__(256) void edge_pass2(
    const float* __restrict__ ef, const int* __restrict__ src, const int* __restrict__ dst,
    const float* __restrict__ e_src, const float* __restrict__ e_dst,
    const float* __restrict__ be, const bf16x8* __restrict__ Wp,
    const float* __restrict__ est, const float* __restrict__ gam,
    const float* __restrict__ bet, float* __restrict__ y, float invE, int ntiles)
{
  int lane = threadIdx.x & 63;
  int gw = blockIdx.x*4 + (threadIdx.x>>6);
  int nw = gridDim.x*4;
  int g = lane>>4, c = lane&15;
  bf16x8 B0[4], B1[4];
  #pragma unroll
  for (int nt=0;nt<4;nt++){ B0[nt]=Wp[(16+nt)*64+lane]; B1[nt]=Wp[(20+nt)*64+lane]; }
  float bias[4], aa[4], bb2[4];
  #pragma unroll
  for (int nt=0;nt<4;nt++){
    int col = c + nt*16;
    bias[nt] = be[col];
    float mu = est[col]*invE;
    float var = est[64+col]*invE - mu*mu;
    float rs = rsqrtf(var + 1e-5f);
    float ga = gam[col]*rs;
    aa[nt] = ga; bb2[nt] = bet[col] - mu*ga;
  }
  for (int t=gw; t<ntiles; t+=nw){
    long base = (long)t*16;
    const float* rp = ef + (base+c)*64 + g*8;
    float4 a0=*(const float4*)rp,      a1=*(const float4*)(rp+4);
    float4 a2=*(const float4*)(rp+32), a3=*(const float4*)(rp+36);
    bf16x8 A0=cvt8(a0,a1), A1=cvt8(a2,a3);
    f32x4 acc[4];
    #pragma unroll
    for (int nt=0;nt<4;nt++){
      acc[nt]=f32x4{0.f,0.f,0.f,0.f};
      acc[nt]=MFMA(A0,B0[nt],acc[nt]);
      acc[nt]=MFMA(A1,B1[nt],acc[nt]);
    }
    int4 sv = *(const int4*)(src+base+4*g);
    int4 dv = *(const int4*)(dst+base+4*g);
    int se[4]={sv.x,sv.y,sv.z,sv.w};
    int de[4]={dv.x,dv.y,dv.z,dv.w};
    #pragma unroll
    for (int e=0;e<4;e++){
      long so=(long)se[e]*64, dd=(long)de[e]*64;
      long er = base + 4*g + e;
      #pragma unroll
      for (int nt=0;nt<4;nt++){
        int col=c+nt*16;
        float mv = acc[nt][e] + e_src[so+col] + e_dst[dd+col] + bias[nt];
        float z = mv*aa[nt] + bb2[nt];
        float sil = z/(1.f+__expf(-z));
        y[er*64+col] = ef[er*64+col] + sil;
      }
    }
  }
}

extern "C" void kernel_launch(void* const* d_in, const int* in_sizes, int n_in,
                              void* d_out, int out_size, void* d_ws, size_t ws_size,
                              hipStream_t stream){
  const float* nf  = (const float*)d_in[0];
  const float* ef  = (const float*)d_in[1];
  const int*   src = (const int*)d_in[2];
  const int*   dst = (const int*)d_in[3];
  const float* W_sg=(const float*)d_in[4];  const float* b_sg=(const float*)d_in[5];
  const float* W_dg=(const float*)d_in[6];  const float* b_dg=(const float*)d_in[7];
  const float* W_eg=(const float*)d_in[8];  const float* b_eg=(const float*)d_in[9];
  const float* W_su=(const float*)d_in[10]; const float* b_su=(const float*)d_in[11];
  const float* W_du=(const float*)d_in[12]; const float* b_du=(const float*)d_in[13];
  const float* gn=(const float*)d_in[14];   const float* btn=(const float*)d_in[15];
  const float* ge=(const float*)d_in[16];   const float* bte=(const float*)d_in[17];

  int Nn = in_sizes[0]/64;
  int Ee = in_sizes[2];
  size_t Nf = (size_t)Nn*64;

  float* ws    = (float*)d_ws;
  float* A_src = ws;                 // becomes x_pre in place
  float* e_src = ws + Nf;
  float* e_dst = ws + 2*Nf;
  int*   cnt   = (int*)(ws + 3*Nf);          // N
  int*   cnt2  = cnt + Nn;                   // N
  float* est   = (float*)(cnt2 + Nn);        // 128
  float* nst   = est + 128;                  // 128
  int*   rowp  = (int*)(nst + 128);          // N+1
  size_t off   = 3*Nf + 2*(size_t)Nn + 256 + (size_t)Nn + 1;
  off = (off + 3) & ~(size_t)3;
  int2*  pairs = (int2*)(ws + off);          // E int2
  size_t off2  = off + 2*(size_t)Ee;
  off2 = (off2 + 3) & ~(size_t)3;
  bf16x8* Wp   = (bf16x8*)(ws + off2);

  float* xo = (float*)d_out;
  float* yo = xo + Nf;

  // zero: cnt, cnt2, est, nst (contiguous)
  hipMemsetAsync(cnt, 0, (2*(size_t)Nn + 256)*sizeof(int), stream);

  wcvt<<<10,256,0,stream>>>(W_sg,W_dg,W_eg,W_su,W_du,Wp);

  int ntn = Nn/16;
  node_xform<<<(ntn+3)/4,256,0,stream>>>(nf,Wp,b_sg,b_dg,b_su,
                                         e_src,e_dst,A_src,ntn);
  hist_k<<<2048,256,0,stream>>>(dst,cnt,Ee);
  scan_k<<<1,1024,0,stream>>>(cnt,rowp,Nn);
  fill_k<<<2048,256,0,stream>>>(src,dst,rowp,cnt2,pairs,Ee);
  aggregate<<<4096,256,0,stream>>>(ef,nf,pairs,rowp,e_dst,b_sg,b_eg,b_du,Wp,
                                   A_src,est,nst,Nn);
  node_final<<<2048,256,0,stream>>>(nf,A_src,nst,gn,btn,xo,Nn);
  int nte = Ee/16;
  edge_pass2<<<2048,256,0,stream>>>(ef,src,dst,e_src,e_dst,b_eg,Wp,est,ge,bte,yo,
                                    1.f/(float)Ee,nte);
}

// Round 4
// 1031.556 us; speedup vs baseline: 1.3657x; 1.3657x over previous
//
#include <hip/hip_runtime.h>
#include <hip/hip_bf16.h>

typedef __attribute__((ext_vector_type(8))) __bf16 bf16x8;
typedef __attribute__((ext_vector_type(4))) float f32x4;

#define MFMA(a,b,c) __builtin_amdgcn_mfma_f32_16x16x32_bf16((a),(b),(c),0,0,0)

__device__ __forceinline__ bf16x8 cvt8(float4 a, float4 b){
  bf16x8 r;
  r[0]=(__bf16)a.x; r[1]=(__bf16)a.y; r[2]=(__bf16)a.z; r[3]=(__bf16)a.w;
  r[4]=(__bf16)b.x; r[5]=(__bf16)b.y; r[6]=(__bf16)b.z; r[7]=(__bf16)b.w;
  return r;
}

// Pack 5 weight matrices [64][64] f32 into bf16 MFMA B-fragments.
// Wp[(m*8 + kt*4 + nt)*64 + lane]: lane holds B[k=kt*32+(l>>4)*8+j][n=nt*16+(l&15)]
__global__ void wcvt(const float* __restrict__ W0, const float* __restrict__ W1,
                     const float* __restrict__ W2, const float* __restrict__ W3,
                     const float* __restrict__ W4, bf16x8* __restrict__ Wp){
  int tid = blockIdx.x*256 + threadIdx.x;
  if (tid >= 5*8*64) return;
  int lane = tid & 63, frag = (tid>>6)&7, m = tid>>9;
  const float* Ws[5] = {W0,W1,W2,W3,W4};
  const float* W = Ws[m];
  int kt = frag>>2, nt = frag&3, g = lane>>4, c = lane&15;
  bf16x8 v;
  #pragma unroll
  for (int j=0;j<8;j++){
    int k = kt*32 + g*8 + j, n = nt*16 + c;
    v[j] = (__bf16)W[k*64+n];
  }
  Wp[tid] = v;
}

// 3 node transforms: e_src, e_dst, A_src
__global__ __launch_bounds__(256) void node_xform(
    const float* __restrict__ nf, const bf16x8* __restrict__ Wp,
    const float* __restrict__ b_sg, const float* __restrict__ b_dg,
    const float* __restrict__ b_su,
    float* __restrict__ e_src, float* __restrict__ e_dst,
    float* __restrict__ A_src, int ntiles)
{
  int lane = threadIdx.x & 63;
  int gw = blockIdx.x*4 + (threadIdx.x>>6);
  if (gw >= ntiles) return;
  int g = lane>>4, c = lane&15;
  long base = (long)gw*16;
  const float* rp = nf + (base + c)*64 + g*8;
  float4 a0 = *(const float4*)rp,      a1 = *(const float4*)(rp+4);
  float4 a2 = *(const float4*)(rp+32), a3 = *(const float4*)(rp+36);
  bf16x8 A0 = cvt8(a0,a1), A1 = cvt8(a2,a3);
  const float* biases[3] = {b_sg,b_dg,b_su};
  float* outs[3] = {e_src,e_dst,A_src};
  const int mats[3] = {0,1,3};
  #pragma unroll
  for (int i=0;i<3;i++){
    #pragma unroll
    for (int nt=0;nt<4;nt++){
      f32x4 acc = {0.f,0.f,0.f,0.f};
      acc = MFMA(A0, Wp[(mats[i]*8+nt)*64+lane],   acc);
      acc = MFMA(A1, Wp[(mats[i]*8+4+nt)*64+lane], acc);
      int col = c + nt*16;
      float bb = biases[i][col];
      #pragma unroll
      for (int e=0;e<4;e++){
        long row = base + 4*g + e;
        outs[i][row*64 + col] = acc[e] + bb;
      }
    }
  }
}

// ---- CSR build on dst ----
__global__ void hist_k(const int* __restrict__ dst, int* __restrict__ cnt, int E){
  int i = blockIdx.x*256 + threadIdx.x, st = gridDim.x*256;
  for (; i<E; i+=st) atomicAdd(&cnt[dst[i]], 1);
}

__global__ __launch_bounds__(1024) void scan_k(const int* __restrict__ cnt,
                                               int* __restrict__ row, int Nn){
  __shared__ int part[1024];
  int t = threadIdx.x;
  int C = (Nn + 1023) >> 10;
  int lo = t*C;
  int hi = lo + C; if (hi > Nn) hi = Nn;
  int s = 0;
  for (int i=lo; i<hi; i++) s += cnt[i];
  part[t] = s;
  __syncthreads();
  for (int off=1; off<1024; off<<=1){
    int v = part[t];
    int u = (t>=off) ? part[t-off] : 0;
    __syncthreads();
    part[t] = v + u;
    __syncthreads();
  }
  int excl = (t==0) ? 0 : part[t-1];
  for (int i=lo; i<hi; i++){ row[i] = excl; excl += cnt[i]; }
  if (t==1023) row[Nn] = excl;
}

__global__ void fill_k(const int* __restrict__ src, const int* __restrict__ dst,
                       const int* __restrict__ row, int* __restrict__ cnt2,
                       int2* __restrict__ pairs, int E){
  int i = blockIdx.x*256 + threadIdx.x, st = gridDim.x*256;
  for (; i<E; i+=st){
    int d = dst[i];
    int pos = row[d] + atomicAdd(&cnt2[d], 1);
    pairs[pos] = make_int2(i, src[i]);
  }
}

// ---- Gather aggregation: one wave per node, gather {ef,nf} rows,
// recompute e_src/Bh contributions via MFMA against LDS-staged weights.
// No min-occupancy bound: let VGPRs float (~128) to avoid scratch spills.
__global__ __launch_bounds__(256) void aggregate(
    const float* __restrict__ ef, const float* __restrict__ nf,
    const int2* __restrict__ pairs, const int* __restrict__ row,
    const float* __restrict__ e_dst,
    const float* __restrict__ b_sg, const float* __restrict__ b_eg,
    const float* __restrict__ b_du,
    const bf16x8* __restrict__ Wp,
    float* __restrict__ A_src,            // in/out: A_src -> x_pre
    float* __restrict__ est, float* __restrict__ nst, int Nn)
{
  __shared__ bf16x8 wl[24*64];   // frags: 0-7 W_eg, 8-15 W_sg, 16-23 W_du
  __shared__ float sst[256];
  {
    int t = threadIdx.x;
    #pragma unroll
    for (int i=0;i<6;i++){
      int idx = i*256 + t;
      int frag = idx>>6, lane = idx&63;
      int mi = frag>>3, f = frag&7;
      int mat = (mi==0) ? 2 : (mi==1 ? 0 : 4);
      wl[idx] = Wp[(mat*8+f)*64+lane];
    }
    sst[t] = 0.f;
  }
  __syncthreads();

  int lane = threadIdx.x & 63;
  int gw = blockIdx.x*4 + (threadIdx.x>>6);
  int nw = gridDim.x*4;
  int g = lane>>4, c = lane&15;
  float bse[4], bdu[4];            // b_sg+b_eg folded; b_du
  #pragma unroll
  for (int nt=0;nt<4;nt++){
    int col = c + nt*16;
    bse[nt] = b_sg[col] + b_eg[col];
    bdu[nt] = b_du[col];
  }
  float es1[4]={0,0,0,0}, es2[4]={0,0,0,0};
  float ns1=0.f, ns2=0.f;

  for (int n=gw; n<Nn; n+=nw){
    int r0 = row[n];
    int deg = row[n+1] - r0;
    int dm1 = deg - 1;
    float ed[4];
    #pragma unroll
    for (int nt=0;nt<4;nt++) ed[nt] = e_dst[(long)n*64 + c + nt*16];
    float ssa[4]={0,0,0,0}, ssha[4]={0,0,0,0};
    int2 pr = pairs[r0 + ((c < deg) ? c : dm1)];
    for (int base=0; base<deg; base+=16){
      // prefetch next tile's pair (clamped; harmless if last tile)
      int sn = base + 16 + c;
      int2 prn = pairs[r0 + ((sn < deg) ? sn : dm1)];
      const float* rpe = ef + (long)pr.x*64 + g*8;
      const float* rpn = nf + (long)pr.y*64 + g*8;
      float4 e0=*(const float4*)rpe,      e1=*(const float4*)(rpe+4);
      float4 e2=*(const float4*)(rpe+32), e3=*(const float4*)(rpe+36);
      float4 n0=*(const float4*)rpn,      n1=*(const float4*)(rpn+4);
      float4 n2=*(const float4*)(rpn+32), n3=*(const float4*)(rpn+36);
      bf16x8 AE0=cvt8(e0,e1), AE1=cvt8(e2,e3);
      bf16x8 AN0=cvt8(n0,n1), AN1=cvt8(n2,n3);
      int rem = deg - base;
      #pragma unroll
      for (int nt=0;nt<4;nt++){
        f32x4 aM={0.f,0.f,0.f,0.f}, aS={0.f,0.f,0.f,0.f}, aB={0.f,0.f,0.f,0.f};
        aM = MFMA(AE0, wl[(   nt)*64+lane], aM);
        aM = MFMA(AE1, wl[( 4+nt)*64+lane], aM);
        aS = MFMA(AN0, wl[( 8+nt)*64+lane], aS);
        aS = MFMA(AN1, wl[(12+nt)*64+lane], aS);
        aB = MFMA(AN0, wl[(16+nt)*64+lane], aB);
        aB = MFMA(AN1, wl[(20+nt)*64+lane], aB);
        #pragma unroll
        for (int e=0;e<4;e++){
          if (4*g+e < rem){
            float mv = ((aM[e] + aS[e]) + ed[nt]) + bse[nt];
            float sg = 1.f/(1.f+__expf(-mv));
            ssa[nt]  += sg;
            ssha[nt] += (aB[e] + bdu[nt])*sg;
            es1[nt]  += mv;
            es2[nt]  += mv*mv;
          }
        }
      }
      pr = prn;
    }
    #pragma unroll
    for (int nt=0;nt<4;nt++){
      ssa[nt]  += __shfl_xor(ssa[nt],16,64);  ssa[nt]  += __shfl_xor(ssa[nt],32,64);
      ssha[nt] += __shfl_xor(ssha[nt],16,64); ssha[nt] += __shfl_xor(ssha[nt],32,64);
    }
    float sv  = (g==0)?ssa[0] :(g==1)?ssa[1] :(g==2)?ssa[2] :ssa[3];
    float shv = (g==0)?ssha[0]:(g==1)?ssha[1]:(g==2)?ssha[2]:ssha[3];
    float h = shv/(sv+1e-6f);
    long xi = (long)n*64 + c + 16*g;
    float xp = A_src[xi] + h;
    A_src[xi] = xp;
    ns1 += xp; ns2 += xp*xp;
  }

  __syncthreads();
  #pragma unroll
  for (int nt=0;nt<4;nt++){
    atomicAdd(&sst[c+16*nt],    es1[nt]);
    atomicAdd(&sst[64+c+16*nt], es2[nt]);
  }
  atomicAdd(&sst[128 + c + 16*g], ns1);
  atomicAdd(&sst[192 + c + 16*g], ns2);
  __syncthreads();
  if (threadIdx.x < 128) atomicAdd(&est[threadIdx.x], sst[threadIdx.x]);
  else                   atomicAdd(&nst[threadIdx.x-128], sst[threadIdx.x]);
}

// Final x = node_feats + silu(bn(x_pre))
__global__ __launch_bounds__(256) void node_final(
    const float* __restrict__ nf, const float* __restrict__ xpre,
    const float* __restrict__ nst, const float* __restrict__ gam,
    const float* __restrict__ bet, float* __restrict__ xo, int Nn)
{
  long tid = blockIdx.x*blockDim.x + threadIdx.x;
  long stride = (long)gridDim.x*blockDim.x;
  int col = (int)(tid & 63);
  float invN = 1.f/(float)Nn;
  float mu = nst[col]*invN;
  float var = nst[64+col]*invN - mu*mu;
  float rs = rsqrtf(var + 1e-5f);
  float aa = gam[col]*rs;
  float bb = bet[col] - mu*aa;
  long total = (long)Nn*64;
  for (long i=tid; i<total; i+=stride){
    float z = xpre[i]*aa + bb;
    xo[i] = nf[i] + z/(1.f+__expf(-z));
  }
}

// Pass 2 over edges: recompute m, y = ef + silu(bn(m))
__global__ __launch_bounds__(256) void edge_pass2(
    const float* __restrict__ ef, const int* __restrict__ src, const int* __restrict__ dst,
    const float* __restrict__ e_src, const float* __restrict__ e_dst,
    const float* __restrict__ be, const bf16x8* __restrict__ Wp,
    const float* __restrict__ est, const float* __restrict__ gam,
    const float* __restrict__ bet, float* __restrict__ y, float invE, int ntiles)
{
  int lane = threadIdx.x & 63;
  int gw = blockIdx.x*4 + (threadIdx.x>>6);
  int nw = gridDim.x*4;
  int g = lane>>4, c = lane&15;
  bf16x8 B0[4], B1[4];
  #pragma unroll
  for (int nt=0;nt<4;nt++){ B0[nt]=Wp[(16+nt)*64+lane]; B1[nt]=Wp[(20+nt)*64+lane]; }
  float bias[4], aa[4], bb2[4];
  #pragma unroll
  for (int nt=0;nt<4;nt++){
    int col = c + nt*16;
    bias[nt] = be[col];
    float mu = est[col]*invE;
    float var = est[64+col]*invE - mu*mu;
    float rs = rsqrtf(var + 1e-5f);
    float ga = gam[col]*rs;
    aa[nt] = ga; bb2[nt] = bet[col] - mu*ga;
  }
  for (int t=gw; t<ntiles; t+=nw){
    long base = (long)t*16;
    const float* rp = ef + (base+c)*64 + g*8;
    float4 a0=*(const float4*)rp,      a1=*(const float4*)(rp+4);
    float4 a2=*(const float4*)(rp+32), a3=*(const float4*)(rp+36);
    bf16x8 A0=cvt8(a0,a1), A1=cvt8(a2,a3);
    f32x4 acc[4];
    #pragma unroll
    for (int nt=0;nt<4;nt++){
      acc[nt]=f32x4{0.f,0.f,0.f,0.f};
      acc[nt]=MFMA(A0,B0[nt],acc[nt]);
      acc[nt]=MFMA(A1,B1[nt],acc[nt]);
    }
    int4 sv = *(const int4*)(src+base+4*g);
    int4 dv = *(const int4*)(dst+base+4*g);
    int se[4]={sv.x,sv.y,sv.z,sv.w};
    int de[4]={dv.x,dv.y,dv.z,dv.w};
    #pragma unroll
    for (int e=0;e<4;e++){
      long so=(long)se[e]*64, dd=(long)de[e]*64;
      long er = base + 4*g + e;
      #pragma unroll
      for (int nt=0;nt<4;nt++){
        int col=c+nt*16;
        float mv = acc[nt][e] + e_src[so+col] + e_dst[dd+col] + bias[nt];
        float z = mv*aa[nt] + bb2[nt];
        float sil = z/(1.f+__expf(-z));
        y[er*64+col] = ef[er*64+col] + sil;
      }
    }
  }
}

extern "C" void kernel_launch(void* const* d_in, const int* in_sizes, int n_in,
                              void* d_out, int out_size, void* d_ws, size_t ws_size,
                              hipStream_t stream){
  const float* nf  = (const float*)d_in[0];
  const float* ef  = (const float*)d_in[1];
  const int*   src = (const int*)d_in[2];
  const int*   dst = (const int*)d_in[3];
  const float* W_sg=(const float*)d_in[4];  const float* b_sg=(const float*)d_in[5];
  const float* W_dg=(const float*)d_in[6];  const float* b_dg=(const float*)d_in[7];
  const float* W_eg=(const float*)d_in[8];  const float* b_eg=(const float*)d_in[9];
  const float* W_su=(const float*)d_in[10]; const float* b_su=(const float*)d_in[11];
  const float* W_du=(const float*)d_in[12]; const float* b_du=(const float*)d_in[13];
  const float* gn=(const float*)d_in[14];   const float* btn=(const float*)d_in[15];
  const float* ge=(const float*)d_in[16];   const float* bte=(const float*)d_in[17];

  int Nn = in_sizes[0]/64;
  int Ee = in_sizes[2];
  size_t Nf = (size_t)Nn*64;

  float* ws    = (float*)d_ws;
  float* A_src = ws;                 // becomes x_pre in place
  float* e_src = ws + Nf;
  float* e_dst = ws + 2*Nf;
  int*   cnt   = (int*)(ws + 3*Nf);          // N
  int*   cnt2  = cnt + Nn;                   // N
  float* est   = (float*)(cnt2 + Nn);        // 128
  float* nst   = est + 128;                  // 128
  int*   rowp  = (int*)(nst + 128);          // N+1
  size_t off   = 3*Nf + 2*(size_t)Nn + 256 + (size_t)Nn + 1;
  off = (off + 3) & ~(size_t)3;
  int2*  pairs = (int2*)(ws + off);          // E int2
  size_t off2  = off + 2*(size_t)Ee;
  off2 = (off2 + 3) & ~(size_t)3;
  bf16x8* Wp   = (bf16x8*)(ws + off2);

  float* xo = (float*)d_out;
  float* yo = xo + Nf;

  // zero: cnt, cnt2, est, nst (contiguous)
  hipMemsetAsync(cnt, 0, (2*(size_t)Nn + 256)*sizeof(int), stream);

  wcvt<<<10,256,0,stream>>>(W_sg,W_dg,W_eg,W_su,W_du,Wp);

  int ntn = Nn/16;
  node_xform<<<(ntn+3)/4,256,0,stream>>>(nf,Wp,b_sg,b_dg,b_su,
                                         e_src,e_dst,A_src,ntn);
  hist_k<<<2048,256,0,stream>>>(dst,cnt,Ee);
  scan_k<<<1,1024,0,stream>>>(cnt,rowp,Nn);
  fill_k<<<2048,256,0,stream>>>(src,dst,rowp,cnt2,pairs,Ee);
  aggregate<<<8192,256,0,stream>>>(ef,nf,pairs,rowp,e_dst,b_sg,b_eg,b_du,Wp,
                                   A_src,est,nst,Nn);
  node_final<<<2048,256,0,stream>>>(nf,A_src,nst,gn,btn,xo,Nn);
  int nte = Ee/16;
  edge_pass2<<<2048,256,0,stream>>>(ef,src,dst,e_src,e_dst,b_eg,Wp,est,ge,bte,yo,
                                    1.f/(float)Ee,nte);
}